// Round 6
// baseline (221.016 us; speedup 1.0000x reference)
//
#include <hip/hip_runtime.h>
#include <cstddef>
#include <cstdint>

#define NEG_SENT (-1.0e30f)

// =====================================================================
//  W=4096, H=2048, D=768, HID=1024, E=64, CC=64, K=3, SENT_LEN=32, MD=128
//  sent_id[w]=w>>5 -> packed cols s*32+p all valid; eid=off-p+63 in [32,94]
//
//  TRANSPOSED pipeline (R4/R5). Round 6: coalesced staging (16 lanes per
//  row), padded (66) staging slots, fp32 word-half (AWw) + bf16 head-half
//  (AWh), 4 blocks/CU k_fused, fewer tail barriers, depth-3 GEMM1 pipeline.
// =====================================================================

typedef short s8v __attribute__((ext_vector_type(8)));
typedef float f32x4 __attribute__((ext_vector_type(4)));

static __device__ __forceinline__ f32x4 mfma16(s8v a, s8v b, f32x4 c) {
  return __builtin_amdgcn_mfma_f32_16x16x32_bf16(a, b, c, 0, 0, 0);
}
static __device__ __forceinline__ unsigned short f2b(float f) {
  union { float f; unsigned u; } v{f};
  unsigned r = v.u + 0x7FFF + ((v.u >> 16) & 1);
  return (unsigned short)(r >> 16);
}
static __device__ __forceinline__ float b2f(unsigned short u) {
  union { unsigned u; float f; } v{((unsigned)u) << 16};
  return v.f;
}
static __device__ __forceinline__ unsigned pk2(float a, float b) {
#if defined(__gfx950__) && __has_builtin(__builtin_amdgcn_cvt_pk_bf16_f32)
  typedef __bf16 b2t __attribute__((ext_vector_type(2)));
  b2t r = __builtin_amdgcn_cvt_pk_bf16_f32(a, b);
  return __builtin_bit_cast(unsigned, r);
#else
  return (unsigned)f2b(a) | ((unsigned)f2b(b) << 16);
#endif
}
static __device__ __forceinline__ float blo(unsigned u) {
  union { unsigned u; float f; } v{u << 16}; return v.f;
}
static __device__ __forceinline__ float bhi(unsigned u) {
  union { unsigned u; float f; } v{u & 0xffff0000u}; return v.f;
}

// ---------- prep1: words -> A-frags (1536 blocks), w1 -> B-frags (768) -------
__global__ __launch_bounds__(256) void k_prep1(const float* __restrict__ words,
                                               const float* __restrict__ w1,
                                               s8v* __restrict__ wordsF,
                                               s8v* __restrict__ w1F) {
  const int bb = blockIdx.x, t = threadIdx.x;
  if (bb < 1536) {  // words [4096][768] -> A-frag
    const int tid = bb * 256 + t;
    const int lane = tid & 63, ks = (tid >> 6) % 24, mt = tid / 1536;
    const int m = mt * 16 + (lane & 15);
    const int kb = ks * 32 + 8 * (lane >> 4);
    const float* src = words + (size_t)m * 768 + kb;
    const float4 v0 = *reinterpret_cast<const float4*>(src);
    const float4 v1 = *reinterpret_cast<const float4*>(src + 4);
    s8v p;
    p[0] = (short)f2b(v0.x); p[1] = (short)f2b(v0.y);
    p[2] = (short)f2b(v0.z); p[3] = (short)f2b(v0.w);
    p[4] = (short)f2b(v1.x); p[5] = (short)f2b(v1.y);
    p[6] = (short)f2b(v1.z); p[7] = (short)f2b(v1.w);
    wordsF[tid] = p;
  } else {  // w1 -> B-frag (N=2048 combined: z=n>>10 selects head/word half)
    const int tid = (bb - 1536) * 256 + t;
    const int lane = tid & 63, ks = (tid >> 6) % 24, nt = tid / 1536;
    const int n = nt * 16 + (lane & 15);
    const int kb = ks * 32 + 8 * (lane >> 4);
    const int z = n >> 10, col = n & 1023;
    const float* src = w1 + (size_t)(z * 768 + kb) * 1024 + col;
    s8v p;
#pragma unroll
    for (int j = 0; j < 8; ++j) p[j] = (short)f2b(src[(size_t)j * 1024]);
    w1F[tid] = p;
  }
}

// ---------- GEMM1 (0..1023) + small cvt (1024..1165) + embC (1166..1293) -----
__global__ __launch_bounds__(256) void k_g1(
    const s8v* __restrict__ AF, const s8v* __restrict__ BF,
    unsigned short* __restrict__ AWh, float* __restrict__ AWw,
    const float* __restrict__ w1, const float* __restrict__ b1,
    const float* __restrict__ emb, const float* __restrict__ w2,
    const float* __restrict__ w3, const float* __restrict__ c1w,
    s8v* __restrict__ w2F, s8v* __restrict__ w3F, s8v* __restrict__ c1F,
    unsigned short* __restrict__ embCb) {
  const int bx = blockIdx.x, t = threadIdx.x;
  __shared__ float se[64];
  if (bx < 1024) {  // GEMM1: tile 128m x 64n, depth-3 register pipeline
    const int lane = t & 63, w = t >> 6;
    const int mq = w & 1, nq = w >> 1;
    const int mt0 = (bx >> 5) * 8 + mq * 4;   // 4 mtiles per wave
    const int nt0 = (bx & 31) * 4 + nq * 2;   // 2 ntiles per wave
    f32x4 acc[4][2] = {};
    const s8v* Ab = AF + (size_t)mt0 * 24 * 64 + lane;
    const s8v* Bb = BF + (size_t)nt0 * 24 * 64 + lane;
    s8v a[3][4], b[3][2];
#pragma unroll
    for (int s = 0; s < 2; ++s) {
#pragma unroll
      for (int i = 0; i < 4; ++i) a[s][i] = Ab[(size_t)(i * 24 + s) * 64];
#pragma unroll
      for (int j = 0; j < 2; ++j) b[s][j] = Bb[(size_t)(j * 24 + s) * 64];
    }
#pragma unroll
    for (int ks = 0; ks < 24; ++ks) {
      const int cur = ks % 3;
      if (ks + 2 < 24) {
        const int nx = (ks + 2) % 3;
#pragma unroll
        for (int i = 0; i < 4; ++i) a[nx][i] = Ab[(size_t)(i * 24 + ks + 2) * 64];
#pragma unroll
        for (int j = 0; j < 2; ++j) b[nx][j] = Bb[(size_t)(j * 24 + ks + 2) * 64];
      }
#pragma unroll
      for (int i = 0; i < 4; ++i)
#pragma unroll
        for (int j = 0; j < 2; ++j)
          acc[i][j] = mfma16(a[cur][i], b[cur][j], acc[i][j]);
    }
    const int rl = (lane >> 4) * 4, cl2 = lane & 15;
    const bool wordhalf = (bx & 31) >= 16;
#pragma unroll
    for (int i = 0; i < 4; ++i)
#pragma unroll
      for (int j = 0; j < 2; ++j) {
        const int n = (nt0 + j) * 16 + cl2;
#pragma unroll
        for (int r = 0; r < 4; ++r) {
          const int m = (mt0 + i) * 16 + rl + r;
          if (wordhalf)
            AWw[(size_t)m * 1024 + (n - 1024)] = acc[i][j][r];
          else
            AWh[(size_t)m * 1024 + n] = f2b(acc[i][j][r]);
        }
      }
  } else if (bx < 1166) {  // small weights -> B-frags
    const int b = bx - 1024;
    if (b < 128) {  // w2 [1024][256] -> [16 nt][32 ks][64][8]
      const int tid = b * 256 + t;
      const int lane = tid & 63, ks = (tid >> 6) % 32, nt = tid / 2048;
      const int n = nt * 16 + (lane & 15);
      const int kb = ks * 32 + 8 * (lane >> 4);
      s8v p;
#pragma unroll
      for (int j = 0; j < 8; ++j) p[j] = (short)f2b(w2[(size_t)(kb + j) * 256 + n]);
      w2F[tid] = p;
    } else if (b < 136) {  // w3 [256][64] -> [4 nt][8 ks][64][8]
      const int tid = (b - 128) * 256 + t;
      const int lane = tid & 63, ks = (tid >> 6) % 8, nt = tid / 512;
      const int n = nt * 16 + (lane & 15);
      const int kb = ks * 32 + 8 * (lane >> 4);
      s8v p;
#pragma unroll
      for (int j = 0; j < 8; ++j) p[j] = (short)f2b(w3[(size_t)(kb + j) * 64 + n]);
      w3F[tid] = p;
    } else {  // c1w [64][64][3] -> [4 nt][6 ks][64][8], k=tap*64+c
      const int tid = (b - 136) * 256 + t;
      const int lane = tid & 63, ks = (tid >> 6) % 6, nt = tid / 384;
      const int o = nt * 16 + (lane & 15);
      const int kb = ks * 32 + 8 * (lane >> 4);
      s8v p;
#pragma unroll
      for (int j = 0; j < 8; ++j) {
        const int k = kb + j, tap = k >> 6, c = k & 63;
        p[j] = (short)f2b(c1w[(size_t)(o * 64 + c) * 3 + tap]);
      }
      c1F[tid] = p;
    }
  } else {  // embCb[e] = bf16(emb[e] @ w1[1536:1600,:] + b1)
    const int e = bx - 1166;
    if (t < 64) se[t] = emb[e * 64 + t];
    __syncthreads();
    float4 acc = *reinterpret_cast<const float4*>(b1 + 4 * t);
#pragma unroll 8
    for (int d = 0; d < 64; ++d) {
      const float4 wv =
          *reinterpret_cast<const float4*>(w1 + (size_t)(1536 + d) * 1024 + 4 * t);
      const float a = se[d];
      acc.x += a * wv.x; acc.y += a * wv.y; acc.z += a * wv.z; acc.w += a * wv.w;
    }
    uint2 r; r.x = pk2(acc.x, acc.y); r.y = pk2(acc.z, acc.w);
    *reinterpret_cast<uint2*>(embCb + (size_t)e * 1024 + 4 * t) = r;
  }
}

// ---------- fused per-2-head block ----------
__global__ __launch_bounds__(256, 4) void k_fused(
    const int* __restrict__ heads, const unsigned short* __restrict__ AWh,
    const float* __restrict__ AWw, const unsigned short* __restrict__ embCb,
    const s8v* __restrict__ w2F, const float* __restrict__ b2,
    const s8v* __restrict__ w3F, const float* __restrict__ b3,
    const s8v* __restrict__ c1F, const float* __restrict__ c1b,
    const float* __restrict__ c2w, const float* __restrict__ c2b,
    float* __restrict__ out) {
  const int h0 = blockIdx.x * 2;
  const int t = threadIdx.x, lane = t & 63, w = t >> 6;
  const int q = lane >> 4, cl = lane & 15;
  const int hidA = heads[h0], hidB = heads[h0 + 1];
  const int sA_ = hidA >> 5, sB_ = hidB >> 5;

  __shared__ unsigned short sHead[2][1024];             // bf16, 4 KB
  __shared__ __align__(16) char rgn[33792];             // staging dbuf / tail
  s8v* sB1 = reinterpret_cast<s8v*>(rgn);               // ((buf*4+r)*4+ks2)*66+slot
  s8v (*sX2f)[8][64] = reinterpret_cast<s8v(*)[8][64]>(rgn);
  s8v (*sCv)[6][64] = reinterpret_cast<s8v(*)[6][64]>(rgn);
  unsigned short* sX2u = reinterpret_cast<unsigned short*>(rgn);
  unsigned short* sY1b = reinterpret_cast<unsigned short*>(rgn + 24576);

  // sentinel fill of both heads' output rows
  {
    float4 m4; m4.x = m4.y = m4.z = m4.w = NEG_SENT;
    float4* o0 = reinterpret_cast<float4*>(out + (size_t)h0 * 8192);
    float4* o1 = reinterpret_cast<float4*>(out + (size_t)(h0 + 1) * 8192);
#pragma unroll
    for (int i = 0; i < 8; ++i) {
      const int fi = t + (i << 8);
      if ((fi >> 4) != sA_) o0[fi] = m4;
      if ((fi >> 4) != sB_) o1[fi] = m4;
    }
  }

  // head rows: AWh[hid][0:1024] bf16 -> LDS
  {
    const uint2 ha = *reinterpret_cast<const uint2*>(AWh + (size_t)hidA * 1024 + 4 * t);
    const uint2 hb = *reinterpret_cast<const uint2*>(AWh + (size_t)hidB * 1024 + 4 * t);
    *reinterpret_cast<uint2*>(&sHead[0][4 * t]) = ha;
    *reinterpret_cast<uint2*>(&sHead[1][4 * t]) = hb;
  }

  // staging: pass r covers row (t>>4)+16r; 16 lanes cover 128 k coalesced
  const int kpos = (t & 15) * 8;
  const int ks2 = (t & 15) >> 2, kgs = (t & 15) & 3;
  const int slot = (t >> 4) + 16 * kgs;
  int woff[4], eoff[4], hoff[4];
#pragma unroll
  for (int r = 0; r < 4; ++r) {
    const int row = (t >> 4) + 16 * r;
    const int hd = row >> 5, pos = row & 31;
    const int hid = hd ? hidB : hidA;
    const int eid = (hid & 31) - pos + 63;          // [32,94]
    woff[r] = ((hid >> 5) * 32 + pos) * 1024 + kpos;
    eoff[r] = eid * 1024 + kpos;
    hoff[r] = hd * 1024 + kpos;
  }

  float4 pw[4][2]; uint4 pe[4];
#pragma unroll
  for (int r = 0; r < 4; ++r) {
    pw[r][0] = *reinterpret_cast<const float4*>(AWw + woff[r]);
    pw[r][1] = *reinterpret_cast<const float4*>(AWw + woff[r] + 4);
    pe[r] = *reinterpret_cast<const uint4*>(embCb + eoff[r]);
  }
  __syncthreads();  // sHead visible

  f32x4 acc[4][4] = {};  // [i: n2-tile][ntp: p'-tile]

  // stage chunk 0 into buf 0
#pragma unroll
  for (int r = 0; r < 4; ++r) {
    const uint4 hv = *reinterpret_cast<const uint4*>(&sHead[0][0] + hoff[r]);
    uint4 o;
    o.x = pk2(fmaxf(pw[r][0].x + blo(pe[r].x) + blo(hv.x), 0.f),
              fmaxf(pw[r][0].y + bhi(pe[r].x) + bhi(hv.x), 0.f));
    o.y = pk2(fmaxf(pw[r][0].z + blo(pe[r].y) + blo(hv.y), 0.f),
              fmaxf(pw[r][0].w + bhi(pe[r].y) + bhi(hv.y), 0.f));
    o.z = pk2(fmaxf(pw[r][1].x + blo(pe[r].z) + blo(hv.z), 0.f),
              fmaxf(pw[r][1].y + bhi(pe[r].z) + bhi(hv.z), 0.f));
    o.w = pk2(fmaxf(pw[r][1].z + blo(pe[r].w) + blo(hv.w), 0.f),
              fmaxf(pw[r][1].w + bhi(pe[r].w) + bhi(hv.w), 0.f));
    *reinterpret_cast<uint4*>(&sB1[(size_t)(((0 * 4 + r) * 4 + ks2) * 66) + slot]) = o;
  }
  __syncthreads();  // buf0 visible

#pragma unroll
  for (int jc = 0; jc < 8; ++jc) {
    const int buf = jc & 1, nbuf = buf ^ 1;
    if (jc < 7) {  // prefetch chunk jc+1
      const int j1 = (jc + 1) * 128;
#pragma unroll
      for (int r = 0; r < 4; ++r) {
        pw[r][0] = *reinterpret_cast<const float4*>(AWw + woff[r] + j1);
        pw[r][1] = *reinterpret_cast<const float4*>(AWw + woff[r] + j1 + 4);
        pe[r] = *reinterpret_cast<const uint4*>(embCb + eoff[r] + j1);
      }
    }
    // GEMM2' MFMA on buf
    const int ksg0 = jc * 4;
#pragma unroll
    for (int k2 = 0; k2 < 4; ++k2) {
      s8v av[4], bv[4];
#pragma unroll
      for (int i = 0; i < 4; ++i)
        av[i] = w2F[(size_t)((w * 4 + i) * 32 + ksg0 + k2) * 64 + lane];
#pragma unroll
      for (int ntp = 0; ntp < 4; ++ntp)
        bv[ntp] = sB1[(size_t)(((buf * 4 + ntp) * 4 + k2) * 66) + lane];
#pragma unroll
      for (int i = 0; i < 4; ++i)
#pragma unroll
        for (int ntp = 0; ntp < 4; ++ntp)
          acc[i][ntp] = mfma16(av[i], bv[ntp], acc[i][ntp]);
    }
    if (jc < 7) {  // stage chunk jc+1 into nbuf
#pragma unroll
      for (int r = 0; r < 4; ++r) {
        const uint4 hv =
            *reinterpret_cast<const uint4*>(&sHead[0][0] + hoff[r] + (jc + 1) * 128);
        uint4 o;
        o.x = pk2(fmaxf(pw[r][0].x + blo(pe[r].x) + blo(hv.x), 0.f),
                  fmaxf(pw[r][0].y + bhi(pe[r].x) + bhi(hv.x), 0.f));
        o.y = pk2(fmaxf(pw[r][0].z + blo(pe[r].y) + blo(hv.y), 0.f),
                  fmaxf(pw[r][0].w + bhi(pe[r].y) + bhi(hv.y), 0.f));
        o.z = pk2(fmaxf(pw[r][1].x + blo(pe[r].z) + blo(hv.z), 0.f),
                  fmaxf(pw[r][1].y + bhi(pe[r].z) + bhi(hv.z), 0.f));
        o.w = pk2(fmaxf(pw[r][1].z + blo(pe[r].w) + blo(hv.w), 0.f),
                  fmaxf(pw[r][1].w + bhi(pe[r].w) + bhi(hv.w), 0.f));
        *reinterpret_cast<uint4*>(
            &sB1[(size_t)(((nbuf * 4 + r) * 4 + ks2) * 66) + slot]) = o;
      }
    }
    __syncthreads();
  }

  // GEMM2' epilogue: X2^T = relu(acc + b2) -> B-frags at rgn[0,16K)
#pragma unroll
  for (int i = 0; i < 4; ++i) {
    const int n2b = w * 64 + i * 16 + q * 4;
    const float4 bb = *reinterpret_cast<const float4*>(b2 + n2b);
    const int ks3 = n2b >> 5, g3 = (n2b >> 3) & 3, idx0 = n2b & 7;
#pragma unroll
    for (int ntp = 0; ntp < 4; ++ntp) {
      const unsigned u0 = pk2(fmaxf(acc[i][ntp][0] + bb.x, 0.f),
                              fmaxf(acc[i][ntp][1] + bb.y, 0.f));
      const unsigned u1 = pk2(fmaxf(acc[i][ntp][2] + bb.z, 0.f),
                              fmaxf(acc[i][ntp][3] + bb.w, 0.f));
      uint2 uu; uu.x = u0; uu.y = u1;
      *reinterpret_cast<uint2*>(
          sX2u + (((size_t)ntp * 8 + ks3) * 64 + cl + 16 * g3) * 8 + idx0) = uu;
    }
  }
  __syncthreads();

  // GEMM3': X3^T[c][p'] ; wave w -> c-tile w
  f32x4 acc3[4] = {};
#pragma unroll
  for (int ks3 = 0; ks3 < 8; ++ks3) {
    const s8v a = w3F[(size_t)(w * 8 + ks3) * 64 + lane];
#pragma unroll
    for (int ntp = 0; ntp < 4; ++ntp)
      acc3[ntp] = mfma16(a, sX2f[ntp][ks3][lane], acc3[ntp]);
  }
  __syncthreads();  // X2f consumed; conv region may be written

  // conv1' im2col frag writes (+ zero pad slots) into rgn[0,24K)
  {
    const int cb = 16 * w + q * 4;
    const float4 b3v = *reinterpret_cast<const float4*>(b3 + cb);
    const int gC = (cb >> 3) & 3, idx0 = cb & 7, ksb = cb >> 5;
#pragma unroll
    for (int ntp = 0; ntp < 4; ++ntp) {
      const int pp = ntp * 16 + cl, hd = pp >> 5, pos = pp & 31;
      const unsigned u0 = pk2(acc3[ntp][0] + b3v.x, acc3[ntp][1] + b3v.y);
      const unsigned u1 = pk2(acc3[ntp][2] + b3v.z, acc3[ntp][3] + b3v.w);
      uint2 uu; uu.x = u0; uu.y = u1;
#pragma unroll
      for (int tau = 0; tau < 3; ++tau) {
        const int pt = pos + 1 - tau;
        if ((unsigned)pt < 32u) {
          const int ppt = hd * 32 + pt;
          const int ks = 2 * tau + ksb;
          *reinterpret_cast<uint2*>(
              sX2u + (((size_t)(ppt >> 4) * 6 + ks) * 64 + (ppt & 15) + 16 * gC) * 8 +
              idx0) = uu;
        }
      }
    }
    if (t < 32) {  // pad slots: (tau=0, col hd*32) and (tau=2, col hd*32+31)
      const int hd = t >> 4, grp = (t >> 3) & 1;
      const int ksz = (grp ? 4 : 0) + ((t >> 2) & 1), kg = t & 3;
      const int ntpz = 2 * hd + grp, lnz = (grp ? 15 : 0) + 16 * kg;
      uint4 z; z.x = z.y = z.z = z.w = 0;
      *reinterpret_cast<uint4*>(&sCv[ntpz][ksz][lnz]) = z;
    }
  }
  __syncthreads();

  // conv1' MFMA + Y1 write (bf16, region [24K,32.5K)) + Y1 zero pads
  f32x4 accc[4] = {};
#pragma unroll
  for (int ks = 0; ks < 6; ++ks) {
    const s8v a = c1F[(size_t)(w * 6 + ks) * 64 + lane];
#pragma unroll
    for (int ntp = 0; ntp < 4; ++ntp)
      accc[ntp] = mfma16(a, sCv[ntp][ks][lane], accc[ntp]);
  }
  {
    const int o = t >> 2, czi = t & 3;
    const int colz = (czi == 0) ? 0 : (czi == 1) ? 33 : (czi == 2) ? 34 : 67;
    sY1b[o * 68 + colz] = 0;
  }
  {
    const int ob = 16 * w + q * 4;
    const float4 cbv = *reinterpret_cast<const float4*>(c1b + ob);
#pragma unroll
    for (int ntp = 0; ntp < 4; ++ntp) {
      const int pp = ntp * 16 + cl, hd = pp >> 5, pos = pp & 31;
      const int col = hd * 34 + 1 + pos;
      sY1b[(ob + 0) * 68 + col] = f2b(accc[ntp][0] + cbv.x);
      sY1b[(ob + 1) * 68 + col] = f2b(accc[ntp][1] + cbv.y);
      sY1b[(ob + 2) * 68 + col] = f2b(accc[ntp][2] + cbv.z);
      sY1b[(ob + 3) * 68 + col] = f2b(accc[ntp][3] + cbv.w);
    }
  }
  __syncthreads();

  // conv2 (64ch*3tap -> 2) on VALU, K split 2 ways + shuffle reduce, scatter
  {
    const int kq = t & 1, c2 = (t >> 1) & 1, pp = t >> 2;
    const int hd = pp >> 5, pos = pp & 31, col = hd * 34 + 1 + pos;
    float a2 = 0.f;
    const float* wp = c2w + (size_t)(c2 * 64 + kq * 32) * 3;
    const unsigned short* yb = sY1b + (size_t)(kq * 32) * 68 + col;
#pragma unroll
    for (int o = 0; o < 32; ++o) {
      a2 += b2f(yb[o * 68 - 1]) * wp[o * 3 + 0] +
            b2f(yb[o * 68]) * wp[o * 3 + 1] +
            b2f(yb[o * 68 + 1]) * wp[o * 3 + 2];
    }
    a2 += __shfl_xor(a2, 1, 64);
    if (kq == 0) {
      const int hidR = hd ? hidB : hidA;
      const int sR = hidR >> 5, offR = hidR & 31;
      const int rel = offR - pos;
      const bool ok = (c2 == 0) ? (rel >= 0) : (rel <= 0);
      out[(size_t)(h0 + hd) * 8192 + (size_t)(sR * 32 + pos) * 2 + c2] =
          ok ? (a2 + c2b[c2]) : NEG_SENT;
    }
  }
}

extern "C" void kernel_launch(void* const* d_in, const int* in_sizes, int n_in,
                              void* d_out, int out_size, void* d_ws,
                              size_t ws_size, hipStream_t stream) {
  const float* words = (const float*)d_in[1];
  const int* heads = (const int*)d_in[2];
  const float* emb = (const float*)d_in[3];
  const float* w1 = (const float*)d_in[4];
  const float* b1 = (const float*)d_in[5];
  const float* w2 = (const float*)d_in[6];
  const float* b2 = (const float*)d_in[7];
  const float* w3 = (const float*)d_in[8];
  const float* b3 = (const float*)d_in[9];
  const float* c1w = (const float*)d_in[10];
  const float* c1b = (const float*)d_in[11];
  const float* c2w = (const float*)d_in[12];
  const float* c2b = (const float*)d_in[13];
  float* out = (float*)d_out;

  char* ws = (char*)d_ws;
  unsigned short* embCb = (unsigned short*)ws;      ws += 128 * 1024 * 2;
  unsigned short* AWh = (unsigned short*)ws;        ws += 4096 * 1024 * 2;
  float* AWw = (float*)ws;                          ws += 4096 * 1024 * 4;
  s8v* wordsF = (s8v*)ws;                           ws += 393216 * 16;
  s8v* w1F = (s8v*)ws;                              ws += 196608 * 16;
  s8v* w2F = (s8v*)ws;                              ws += 32768 * 16;
  s8v* w3F = (s8v*)ws;                              ws += 2048 * 16;
  s8v* c1F = (s8v*)ws;                              ws += 1536 * 16;

  k_prep1<<<2304, 256, 0, stream>>>(words, w1, wordsF, w1F);
  k_g1<<<1294, 256, 0, stream>>>(wordsF, w1F, AWh, AWw, w1, b1, emb, w2, w3,
                                 c1w, w2F, w3F, c1F, embCb);
  k_fused<<<1024, 256, 0, stream>>>(heads, AWh, AWw, embCb, w2F, b2, w3F, b3,
                                    c1F, c1b, c2w, c2b, out);
}